// Round 2
// baseline (613.179 us; speedup 1.0000x reference)
//
#include <hip/hip_runtime.h>
#include <hip/hip_bf16.h>
#include <math.h>

typedef __bf16 bf16_t;
typedef __bf16 bf16x8 __attribute__((ext_vector_type(8)));
typedef float  f32x4  __attribute__((ext_vector_type(4)));

#define MFMA16(a,b,c) __builtin_amdgcn_mfma_f32_16x16x32_bf16((a),(b),(c),0,0,0)

namespace {
constexpr int D    = 64;
constexpr int DIN  = 192;
constexpr int NN   = 30000;
constexpr int NE   = 480000;
constexpr int TILE = 128;               // edges per block-tile
constexpr int NTILES = NE / TILE;       // 3750 exactly

// padded leading strides (elements) -> uniform LDS bank tiling for b128 reads
constexpr int SW0 = 200;                // W0^T rows [64][200]  (400B row)
constexpr int SW1 = 72;                 // W1^T rows [64][72]   (144B row)
constexpr int SH  = 72;                 // hidden rows [128][72]

constexpr int W0T_SZ = 64 * SW0;        // 12800 elems = 25600 B
constexpr int W1T_SZ = 64 * SW1;        //  4608 elems =  9216 B

// LDS element offsets (total 31232 elems = 62464 B < 64 KB -> 2 blocks/CU)
constexpr int LDS_A = 0;                // 12800: W0T slot / W1T-pair slot
constexpr int LDS_B = 12800;            //  9216: h0 / e_new / g0n
constexpr int LDS_C = 22016;            //  9216: g0 / h0n
constexpr int LDS_TOT = 31232;

constexpr size_t WS_AGG_BYTES = (size_t)NN * D * 4;                  // fp32 agg
constexpr size_t WS_WT_BYTES  = (size_t)(4 * W0T_SZ + 4 * W1T_SZ) * 2;
constexpr size_t WS_FLAG_OFF  = WS_AGG_BYTES + WS_WT_BYTES;
}

// ---- dtype-generic A-fragment / scalar loads (always produce bf16 / float) --
__device__ __forceinline__ bf16x8 ldA(const bf16_t* p) {
  return *(const bf16x8*)p;             // all callsites 16B-aligned
}
__device__ __forceinline__ bf16x8 ldA(const float* p) {
  const float4* q4 = (const float4*)p;  // callsites 32B-aligned
  const float4 u = q4[0], v = q4[1];
  bf16x8 r;
  r[0] = (bf16_t)u.x; r[1] = (bf16_t)u.y; r[2] = (bf16_t)u.z; r[3] = (bf16_t)u.w;
  r[4] = (bf16_t)v.x; r[5] = (bf16_t)v.y; r[6] = (bf16_t)v.z; r[7] = (bf16_t)v.w;
  return r;
}

__device__ __forceinline__ void stage16(bf16_t* l, const bf16_t* g, int elems, int t) {
  int4* ls = (int4*)l; const int4* gs = (const int4*)g;
  const int n = elems >> 3;
  for (int i = t; i < n; i += 256) ls[i] = gs[i];
}

__device__ __forceinline__ float silu_f(float v) { return v / (1.f + __expf(-v)); }
__device__ __forceinline__ float sigm_f(float v) { return 1.f / (1.f + __expf(-v)); }

// layer0: [32 edges x 192] @ [192 x 64].  A-frags gathered from global
// (node_feat rows sA/sB, dA/dB; middle 64 cols from `mid`).  B from LDS W0^T.
template<typename TN, typename TM>
__device__ __forceinline__ void mlp_l0(f32x4 acc[2][4], const bf16_t* __restrict__ w0t,
    const TN* __restrict__ nf, const TM* __restrict__ mid,
    int sA, int sB, int dA, int dB, int midA, int midB, int midStride,
    int m, int q)
{
  const f32x4 z = {0.f, 0.f, 0.f, 0.f};
  #pragma unroll
  for (int mt = 0; mt < 2; ++mt)
    #pragma unroll
    for (int nt = 0; nt < 4; ++nt) acc[mt][nt] = z;
  #pragma unroll
  for (int kt = 0; kt < 6; ++kt) {
    const int ko = (kt & 1) * 32 + q * 8;
    bf16x8 a0, a1;
    if (kt < 2)      { a0 = ldA(nf + sA * D + ko);            a1 = ldA(nf + sB * D + ko); }
    else if (kt < 4) { a0 = ldA(mid + midA * midStride + ko); a1 = ldA(mid + midB * midStride + ko); }
    else             { a0 = ldA(nf + dA * D + ko);            a1 = ldA(nf + dB * D + ko); }
    const bf16_t* wb = w0t + m * SW0 + kt * 32 + q * 8;
    #pragma unroll
    for (int nt = 0; nt < 4; ++nt) {
      const bf16x8 b = ldA(wb + nt * 16 * SW0);
      acc[0][nt] = MFMA16(a0, b, acc[0][nt]);
      acc[1][nt] = MFMA16(a1, b, acc[1][nt]);
    }
  }
}

// layer1: [32 edges x 64] @ [64 x 64], A from LDS hidden, B from LDS W1^T.
__device__ __forceinline__ void mlp_l1(f32x4 acc[2][4], const bf16_t* __restrict__ h,
                                       const bf16_t* __restrict__ w1t,
                                       int leA, int leB, int m, int q)
{
  const f32x4 z = {0.f, 0.f, 0.f, 0.f};
  #pragma unroll
  for (int mt = 0; mt < 2; ++mt)
    #pragma unroll
    for (int nt = 0; nt < 4; ++nt) acc[mt][nt] = z;
  #pragma unroll
  for (int kt = 0; kt < 2; ++kt) {
    const int ko = kt * 32 + q * 8;
    const bf16x8 a0 = ldA(h + leA * SH + ko);
    const bf16x8 a1 = ldA(h + leB * SH + ko);
    const bf16_t* wb = w1t + m * SW1 + ko;
    #pragma unroll
    for (int nt = 0; nt < 4; ++nt) {
      const bf16x8 b = ldA(wb + nt * 16 * SW1);
      acc[0][nt] = MFMA16(a0, b, acc[0][nt]);
      acc[1][nt] = MFMA16(a1, b, acc[1][nt]);
    }
  }
}

// C-layout acc (+bias, silu) -> LDS hidden [le][n] as bf16
template<typename TB>
__device__ __forceinline__ void hidden_silu(const f32x4 acc[2][4],
    const TB* __restrict__ bias, bf16_t* __restrict__ h, int w, int m, int q)
{
  #pragma unroll
  for (int nt = 0; nt < 4; ++nt) {
    const float bv = (float)bias[nt * 16 + m];
    #pragma unroll
    for (int mt = 0; mt < 2; ++mt) {
      #pragma unroll
      for (int r = 0; r < 4; ++r) {
        const float v = acc[mt][nt][r] + bv;
        h[(w * 32 + mt * 16 + q * 4 + r) * SH + nt * 16 + m] = (bf16_t)silu_f(v);
      }
    }
  }
}

// ---- dtype detection: even-index uint16s of an fp32 buffer have uniform
// exponent fields; of a bf16 buffer they are real bf16 values (exp ~113-126).
__global__ void detect_kernel(const void* w0, int* flag) {
  __shared__ int cnt;
  if (threadIdx.x == 0) cnt = 0;
  __syncthreads();
  const unsigned short* u = (const unsigned short*)w0;
  const unsigned short v = u[2 * threadIdx.x];       // 256 even-index samples
  const int e = (v >> 7) & 0xFF;
  atomicAdd(&cnt, (e >= 100 && e <= 140) ? 1 : 0);
  __syncthreads();
  if (threadIdx.x == 0) *flag = (cnt >= 128) ? 1 : 0;  // 1 = bf16, 0 = fp32
}

struct PrepArgs { const void* w[8]; bf16_t* o[8]; };

// transpose weights into ws as bf16:  W^T[n][k] = W[k][n], padded strides
template<typename T>
__global__ void prep_kernel(const int* flag, int want, PrepArgs a) {
  if (*flag != want) return;
  const int b = blockIdx.x, t = threadIdx.x;
  const T* w = (const T*)a.w[b];
  bf16_t* o = a.o[b];
  if (b < 4) {
    for (int i = t; i < DIN * D; i += 256) o[(i & 63) * SW0 + (i >> 6)] = (bf16_t)(float)w[i];
  } else {
    for (int i = t; i < D * D; i += 256) o[(i & 63) * SW1 + (i >> 6)] = (bf16_t)(float)w[i];
  }
}

template<typename T>
__global__ __launch_bounds__(256, 2) void fused_kernel(
    const int* __restrict__ flag, int want,
    const T* __restrict__ nf, const T* __restrict__ ef,
    const int* __restrict__ src, const int* __restrict__ dst,
    const T* __restrict__ eLb0, const T* __restrict__ eLb1,
    const T* __restrict__ eGb0, const T* __restrict__ eGb1,
    const T* __restrict__ nLb0, const T* __restrict__ nLb1,
    const T* __restrict__ nGb0, const T* __restrict__ nGb1,
    const bf16_t* __restrict__ wt, float* __restrict__ agg,
    T* __restrict__ out_e)
{
  if (*flag != want) return;
  __shared__ __align__(16) bf16_t sm[LDS_TOT];
  const int t = threadIdx.x;
  const int lane = t & 63;
  const int w = t >> 6;        // wave 0..3, owns 32 edges of the 128-edge tile
  const int m = lane & 15;     // M-index (A) / N-index (C)
  const int q = lane >> 4;     // quad

  const bf16_t* w0t_eL = wt;
  const bf16_t* w0t_eG = wt + W0T_SZ;
  const bf16_t* w0t_nL = wt + 2 * W0T_SZ;
  const bf16_t* w0t_nG = wt + 3 * W0T_SZ;
  const bf16_t* w1t_e  = wt + 4 * W0T_SZ;                  // [L | G]
  const bf16_t* w1t_n  = wt + 4 * W0T_SZ + 2 * W1T_SZ;     // [L | G]

  for (int tile = blockIdx.x; tile < NTILES; tile += gridDim.x) {
    const int e0  = tile * TILE;
    const int eA  = e0 + w * 32 + m;
    const int eB  = eA + 16;
    const int leA = w * 32 + m;
    const int leB = leA + 16;
    const int sA = src[eA], sB = src[eB];
    const int dA = dst[eA], dB = dst[eB];

    f32x4 acc[2][4], acg[2][4];

    // ===== edge MLP, layer0, layers branch -> h0 (B) =====
    stage16(sm + LDS_A, w0t_eL, W0T_SZ, t);
    __syncthreads();
    mlp_l0(acc, sm + LDS_A, nf, ef, sA, sB, dA, dB, eA, eB, D, m, q);
    hidden_silu(acc, eLb0, sm + LDS_B, w, m, q);
    __syncthreads();
    // ===== edge MLP, layer0, gates branch -> g0 (C) =====
    stage16(sm + LDS_A, w0t_eG, W0T_SZ, t);
    __syncthreads();
    mlp_l0(acc, sm + LDS_A, nf, ef, sA, sB, dA, dB, eA, eB, D, m, q);
    hidden_silu(acc, eGb0, sm + LDS_C, w, m, q);
    __syncthreads();
    // ===== edge MLP, layer1 both branches =====
    stage16(sm + LDS_A, w1t_e, 2 * W1T_SZ, t);
    __syncthreads();
    mlp_l1(acc, sm + LDS_B, sm + LDS_A,          leA, leB, m, q);  // h1
    mlp_l1(acg, sm + LDS_C, sm + LDS_A + W1T_SZ, leA, leB, m, q);  // g1

    bf16_t ev[2][4][4];
    #pragma unroll
    for (int nt = 0; nt < 4; ++nt) {
      const int n = nt * 16 + m;
      const float bL = (float)eLb1[n];
      const float bG = (float)eGb1[n];
      #pragma unroll
      for (int mt = 0; mt < 2; ++mt) {
        #pragma unroll
        for (int r = 0; r < 4; ++r) {
          const int e = e0 + w * 32 + mt * 16 + q * 4 + r;
          const float hv = silu_f(acc[mt][nt][r] + bL);
          const float gv = sigm_f(acg[mt][nt][r] + bG);
          const float val = (float)ef[e * D + n] + hv * gv;
          ev[mt][nt][r] = (bf16_t)val;
          out_e[e * D + n] = (T)val;             // e_new output (full prec if T=float)
        }
      }
    }
    __syncthreads();          // h0/g0 + w1t_e reads finished -> B reusable
    #pragma unroll
    for (int nt = 0; nt < 4; ++nt)
      #pragma unroll
      for (int mt = 0; mt < 2; ++mt)
        #pragma unroll
        for (int r = 0; r < 4; ++r)
          sm[LDS_B + (w * 32 + mt * 16 + q * 4 + r) * SH + nt * 16 + m] = ev[mt][nt][r];
    __syncthreads();

    // ===== node MLP, layer0, layers -> h0n (C) =====
    stage16(sm + LDS_A, w0t_nL, W0T_SZ, t);
    __syncthreads();
    mlp_l0(acc, sm + LDS_A, nf, sm + LDS_B, sA, sB, dA, dB, leA, leB, SH, m, q);
    hidden_silu(acc, nLb0, sm + LDS_C, w, m, q);
    __syncthreads();
    // ===== node MLP, layer0, gates -> g0n (B, after e_new reads done) =====
    stage16(sm + LDS_A, w0t_nG, W0T_SZ, t);
    __syncthreads();
    mlp_l0(acc, sm + LDS_A, nf, sm + LDS_B, sA, sB, dA, dB, leA, leB, SH, m, q);
    __syncthreads();          // all e_new reads finished -> B reusable
    hidden_silu(acc, nGb0, sm + LDS_B, w, m, q);
    __syncthreads();
    // ===== node MLP, layer1 both branches =====
    stage16(sm + LDS_A, w1t_n, 2 * W1T_SZ, t);
    __syncthreads();
    mlp_l1(acc, sm + LDS_C, sm + LDS_A,          leA, leB, m, q);  // h1n
    mlp_l1(acg, sm + LDS_B, sm + LDS_A + W1T_SZ, leA, leB, m, q);  // g1n

    int d8[2][4];
    #pragma unroll
    for (int mt = 0; mt < 2; ++mt)
      #pragma unroll
      for (int r = 0; r < 4; ++r)
        d8[mt][r] = dst[e0 + w * 32 + mt * 16 + q * 4 + r];

    #pragma unroll
    for (int nt = 0; nt < 4; ++nt) {
      const int n = nt * 16 + m;
      const float bL = (float)nLb1[n];
      const float bG = (float)nGb1[n];
      #pragma unroll
      for (int mt = 0; mt < 2; ++mt) {
        #pragma unroll
        for (int r = 0; r < 4; ++r) {
          const float hv = silu_f(acc[mt][nt][r] + bL);
          const float gv = sigm_f(acg[mt][nt][r] + bG);
          atomicAdd(&agg[d8[mt][r] * D + n], hv * gv);
        }
      }
    }
    __syncthreads();          // protect LDS before next tile's staging
  }
}

// h_new = node_feat + agg @ node_out_W   (one wave per node)
template<typename T>
__global__ __launch_bounds__(256) void node_out_kernel(
    const int* __restrict__ flag, int want,
    const T* __restrict__ nf, const float* __restrict__ agg,
    const T* __restrict__ Wo, T* __restrict__ out_h)
{
  if (*flag != want) return;
  __shared__ float wsh[D * D];
  const int t = threadIdx.x;
  for (int i = t; i < D * D; i += 256) wsh[i] = (float)Wo[i];
  __syncthreads();
  const int node = blockIdx.x * 4 + (t >> 6);
  const int j = t & 63;
  const float* arow = agg + node * D;
  float acc = 0.f;
  #pragma unroll
  for (int k = 0; k < D; ++k) acc = fmaf(arow[k], wsh[k * D + j], acc);
  out_h[node * D + j] = (T)((float)nf[node * D + j] + acc);
}

template<typename T>
static void launch_all(void* const* d_in, void* d_out, void* d_ws,
                       const int* flag, int want, bf16_t* wt, float* agg,
                       hipStream_t stream) {
  const T* nf  = (const T*)d_in[0];
  const T* ef  = (const T*)d_in[1];
  const int* src = (const int*)d_in[2];
  const int* dst = (const int*)d_in[3];
  T* out_h = (T*)d_out;
  T* out_e = out_h + (size_t)NN * D;

  fused_kernel<T><<<512, 256, 0, stream>>>(flag, want, nf, ef, src, dst,
      (const T*)d_in[5],  (const T*)d_in[7],   // eLb0, eLb1
      (const T*)d_in[9],  (const T*)d_in[11],  // eGb0, eGb1
      (const T*)d_in[13], (const T*)d_in[15],  // nLb0, nLb1
      (const T*)d_in[17], (const T*)d_in[19],  // nGb0, nGb1
      wt, agg, out_e);
  node_out_kernel<T><<<NN / 4, 256, 0, stream>>>(flag, want, nf, agg,
      (const T*)d_in[20], out_h);
}

extern "C" void kernel_launch(void* const* d_in, const int* in_sizes, int n_in,
                              void* d_out, int out_size, void* d_ws, size_t ws_size,
                              hipStream_t stream) {
  float*  agg  = (float*)d_ws;
  bf16_t* wt   = (bf16_t*)((char*)d_ws + WS_AGG_BYTES);
  int*    flag = (int*)((char*)d_ws + WS_FLAG_OFF);

  hipMemsetAsync(d_ws, 0, WS_AGG_BYTES, stream);       // zero agg

  detect_kernel<<<1, 256, 0, stream>>>(d_in[4], flag); // probe eLW0 dtype

  PrepArgs pa;
  pa.w[0] = d_in[4];  pa.w[1] = d_in[8];  pa.w[2] = d_in[12]; pa.w[3] = d_in[16]; // W0s: eL,eG,nL,nG
  pa.w[4] = d_in[6];  pa.w[5] = d_in[10]; pa.w[6] = d_in[14]; pa.w[7] = d_in[18]; // W1s
  for (int i = 0; i < 4; ++i) pa.o[i]     = wt + i * W0T_SZ;
  for (int j = 0; j < 4; ++j) pa.o[4 + j] = wt + 4 * W0T_SZ + j * W1T_SZ;
  prep_kernel<float> <<<8, 256, 0, stream>>>(flag, 0, pa);
  prep_kernel<bf16_t><<<8, 256, 0, stream>>>(flag, 1, pa);

  launch_all<float> (d_in, d_out, d_ws, flag, 0, wt, agg, stream);
  launch_all<bf16_t>(d_in, d_out, d_ws, flag, 1, wt, agg, stream);
}